// Round 4
// baseline (240.771 us; speedup 1.0000x reference)
//
#include <hip/hip_runtime.h>

// ---------------------------------------------------------------------------
// MixedFeedForward: out = relu(x·(s⊙w0)^T + sb0⊙b0)·(s⊙w1)^T + sb1⊙b1
// where s(h,d) = Σ_{ie: d<E[ie]} a[ie] · Σ_{ir: h<E[ie]*R[ir]} b[ir],
//       a = softmax(arch_embed), b = softmax(arch_mlp).
// Strategy: fold masks into bf16 weight copies, then two bf16 MFMA GEMMs
// (m97-structure: 128x128 tile, BK=64, 4 waves, global_load_lds width 16).
// ---------------------------------------------------------------------------

typedef __attribute__((ext_vector_type(8))) short bf16x8;   // 8 bf16 = 4 VGPR
typedef __attribute__((ext_vector_type(4))) float f32x4;
typedef __attribute__((ext_vector_type(8))) unsigned short u16x8;

__device__ __forceinline__ unsigned short f2bf(float f) {
  unsigned int x = __float_as_uint(f);
  x += 0x7fffu + ((x >> 16) & 1u);        // round-to-nearest-even
  return (unsigned short)(x >> 16);
}

__device__ __forceinline__ void softmax3(const float* __restrict__ p, float* o) {
  float m = fmaxf(p[0], fmaxf(p[1], p[2]));
  float e0 = expf(p[0] - m), e1 = expf(p[1] - m), e2 = expf(p[2] - m);
  float inv = 1.0f / (e0 + e1 + e2);
  o[0] = e0 * inv; o[1] = e1 * inv; o[2] = e2 * inv;
}

// s(h,d); sval(h,0) = bm0[h] row-bias scale; sval(0,d) = bm1[d] col-bias scale
__device__ __forceinline__ float sval(int h, int d, const float a[3], const float b[3]) {
  constexpr int E[3] = {512, 768, 1024};
  constexpr int R[3] = {2, 3, 4};
  float s = 0.f;
#pragma unroll
  for (int ie = 0; ie < 3; ++ie) {
    if (d < E[ie]) {
      float t = 0.f;
#pragma unroll
      for (int ir = 0; ir < 3; ++ir)
        if (h < E[ie] * R[ir]) t += b[ir];
      s += a[ie] * t;
    }
  }
  return s;
}

// ---------------- prep kernels (memory-bound, vectorized 8 elems/thread) ----

__global__ __launch_bounds__(256) void conv_x(const float* __restrict__ x,
                                              unsigned short* __restrict__ o,
                                              int n8) {
  int t = blockIdx.x * 256 + threadIdx.x;
  if (t >= n8) return;
  const f32x4* p = (const f32x4*)(x + (size_t)t * 8);
  f32x4 v0 = p[0], v1 = p[1];
  u16x8 r;
#pragma unroll
  for (int j = 0; j < 4; ++j) { r[j] = f2bf(v0[j]); r[4 + j] = f2bf(v1[j]); }
  *(u16x8*)(o + (size_t)t * 8) = r;
}

// w0: [4096][1024], elem (h,d). 8 consecutive d share one s (boundaries %8==0).
__global__ __launch_bounds__(256) void conv_w0(const float* __restrict__ w,
                                               const float* __restrict__ ae,
                                               const float* __restrict__ am,
                                               unsigned short* __restrict__ o) {
  int t = blockIdx.x * 256 + threadIdx.x;   // < 524288
  int base = t * 8;
  int h = base >> 10, d = base & 1023;
  float a[3], b[3];
  softmax3(ae, a); softmax3(am, b);
  float s = sval(h, d, a, b);
  const f32x4* p = (const f32x4*)(w + (size_t)base);
  f32x4 v0 = p[0], v1 = p[1];
  u16x8 r;
#pragma unroll
  for (int j = 0; j < 4; ++j) { r[j] = f2bf(v0[j] * s); r[4 + j] = f2bf(v1[j] * s); }
  *(u16x8*)(o + (size_t)base) = r;
}

// w1: [1024][4096], elem (d,h). 8 consecutive h share one s (thresholds %8==0).
__global__ __launch_bounds__(256) void conv_w1(const float* __restrict__ w,
                                               const float* __restrict__ ae,
                                               const float* __restrict__ am,
                                               unsigned short* __restrict__ o) {
  int t = blockIdx.x * 256 + threadIdx.x;   // < 524288
  int base = t * 8;
  int d = base >> 12, h = base & 4095;
  float a[3], b[3];
  softmax3(ae, a); softmax3(am, b);
  float s = sval(h, d, a, b);
  const f32x4* p = (const f32x4*)(w + (size_t)base);
  f32x4 v0 = p[0], v1 = p[1];
  u16x8 r;
#pragma unroll
  for (int j = 0; j < 4; ++j) { r[j] = f2bf(v0[j] * s); r[4 + j] = f2bf(v1[j] * s); }
  *(u16x8*)(o + (size_t)base) = r;
}

__global__ __launch_bounds__(256) void conv_bias(const float* __restrict__ b0,
                                                 const float* __restrict__ b1,
                                                 const float* __restrict__ ae,
                                                 const float* __restrict__ am,
                                                 float* __restrict__ bb0,
                                                 float* __restrict__ bb1) {
  int i = blockIdx.x * 256 + threadIdx.x;
  float a[3], b[3];
  softmax3(ae, a); softmax3(am, b);
  if (i < 4096) bb0[i] = sval(i, 0, a, b) * b0[i];
  int d = i - 4096;
  if (d >= 0 && d < 1024) bb1[d] = sval(0, d, a, b) * b1[d];
}

// ---------------- bf16 MFMA GEMM, B^T layout (m97 structure) ----------------
// C[M][N] = A[M][K] · B[N][K]^T  (+bias[N]); MODE 0: relu + bf16 store (H),
// MODE 1: f32 store (d_out). 128x128 tile, BK=64, 4 waves (2x2 of 64x64).

template <int MODE>
__global__ __launch_bounds__(256) void gemm_bt(const unsigned short* __restrict__ A,
                                               const unsigned short* __restrict__ B,
                                               const float* __restrict__ bias,
                                               void* __restrict__ Cout,
                                               int M, int N, int K) {
  __shared__ unsigned short As[128 * 64];   // 16 KiB
  __shared__ unsigned short Bs[128 * 64];   // 16 KiB

  const int tid  = threadIdx.x;
  const int lane = tid & 63;
  const int w    = tid >> 6;
  const int m0   = blockIdx.x * 128;
  const int n0   = blockIdx.y * 128;
  const int wm   = (w >> 1) * 64;
  const int wn   = (w & 1) * 64;

  f32x4 acc[4][4] = {};

  // staging geometry: thread t covers 8 bf16 (16 B); 256 threads = 32 rows/iter
  const int srow = tid >> 3;          // 0..31
  const int scol = (tid & 7) * 8;     // 0,8,...,56
  const unsigned short* Ag = A + (size_t)(m0 + srow) * K + scol;
  const unsigned short* Bg = B + (size_t)(n0 + srow) * K + scol;
  unsigned short* Asl = As + tid * 8; // lane-linear dest (wave-uniform base + lane*16B)
  unsigned short* Bsl = Bs + tid * 8;

  for (int k0 = 0; k0 < K; k0 += 64) {
    __syncthreads();                  // prev tile consumed before overwrite
#pragma unroll
    for (int i = 0; i < 4; ++i) {
      __builtin_amdgcn_global_load_lds(
          (const __attribute__((address_space(1))) void*)(Ag + (size_t)(i * 32) * K + k0),
          (__attribute__((address_space(3))) void*)(Asl + i * 2048), 16, 0, 0);
      __builtin_amdgcn_global_load_lds(
          (const __attribute__((address_space(1))) void*)(Bg + (size_t)(i * 32) * K + k0),
          (__attribute__((address_space(3))) void*)(Bsl + i * 2048), 16, 0, 0);
    }
    asm volatile("s_waitcnt vmcnt(0)" ::: "memory");
    __syncthreads();

#pragma unroll
    for (int ks = 0; ks < 2; ++ks) {
      const int ko = ks * 32 + (lane >> 4) * 8;
      bf16x8 af[4], bfr[4];
#pragma unroll
      for (int m = 0; m < 4; ++m)
        af[m] = *(const bf16x8*)&As[(wm + m * 16 + (lane & 15)) * 64 + ko];
#pragma unroll
      for (int n = 0; n < 4; ++n)
        bfr[n] = *(const bf16x8*)&Bs[(wn + n * 16 + (lane & 15)) * 64 + ko];
#pragma unroll
      for (int m = 0; m < 4; ++m)
#pragma unroll
        for (int n = 0; n < 4; ++n)
          acc[m][n] = __builtin_amdgcn_mfma_f32_16x16x32_bf16(af[m], bfr[n], acc[m][n], 0, 0, 0);
    }
  }

  // epilogue: C/D layout col=lane&15, row=(lane>>4)*4+reg  [m89-verified]
  const int crow = (lane >> 4) * 4;
  const int ccol = lane & 15;
#pragma unroll
  for (int m = 0; m < 4; ++m) {
#pragma unroll
    for (int n = 0; n < 4; ++n) {
      const int gr = m0 + wm + m * 16 + crow;
      const int gc = n0 + wn + n * 16 + ccol;
      const float bv = bias[gc];
      if (MODE == 0) {
        unsigned short* H = (unsigned short*)Cout;
#pragma unroll
        for (int r = 0; r < 4; ++r) {
          float v = fmaxf(acc[m][n][r] + bv, 0.f);
          H[(size_t)(gr + r) * N + gc] = f2bf(v);
        }
      } else {
        float* C = (float*)Cout;
#pragma unroll
        for (int r = 0; r < 4; ++r)
          C[(size_t)(gr + r) * N + gc] = acc[m][n][r] + bv;
      }
    }
  }
}

// ---------------------------------------------------------------------------

extern "C" void kernel_launch(void* const* d_in, const int* in_sizes, int n_in,
                              void* d_out, int out_size, void* d_ws, size_t ws_size,
                              hipStream_t stream) {
  const float* x  = (const float*)d_in[0];   // [8,512,1024]
  const float* w0 = (const float*)d_in[1];   // [4096,1024]
  const float* b0 = (const float*)d_in[2];   // [4096]
  const float* w1 = (const float*)d_in[3];   // [1024,4096]
  const float* b1 = (const float*)d_in[4];   // [1024]
  const float* ae = (const float*)d_in[5];   // [3]
  const float* am = (const float*)d_in[6];   // [3]

  char* ws = (char*)d_ws;
  unsigned short* xb   = (unsigned short*)(ws);                    //  8 MiB
  unsigned short* w0e  = (unsigned short*)(ws + (8u  << 20));      //  8 MiB
  unsigned short* w1e  = (unsigned short*)(ws + (16u << 20));      //  8 MiB
  unsigned short* Hbuf = (unsigned short*)(ws + (24u << 20));      // 32 MiB
  float* bb0 = (float*)(ws + (56u << 20));                         // 16 KiB
  float* bb1 = (float*)(ws + (56u << 20) + 16384);                 //  4 KiB

  conv_x  <<<2048, 256, 0, stream>>>(x, xb, 524288);
  conv_w0 <<<2048, 256, 0, stream>>>(w0, ae, am, w0e);
  conv_w1 <<<2048, 256, 0, stream>>>(w1, ae, am, w1e);
  conv_bias<<<20, 256, 0, stream>>>(b0, b1, ae, am, bb0, bb1);

  dim3 g1(32, 32);  // M/128 x N/128
  gemm_bt<0><<<g1, 256, 0, stream>>>(xb, w0e, bb0, Hbuf, 4096, 4096, 1024);
  dim3 g2(32, 8);
  gemm_bt<1><<<g2, 256, 0, stream>>>(Hbuf, w1e, bb1, d_out, 4096, 1024, 4096);
}

// Round 5
// 223.597 us; speedup vs baseline: 1.0768x; 1.0768x over previous
//
#include <hip/hip_runtime.h>

// ---------------------------------------------------------------------------
// MixedFeedForward: out = relu(x·(s⊙w0)^T + sb0⊙b0)·(s⊙w1)^T + sb1⊙b1
// s(h,d) piecewise-constant DARTS mask field; folded into bf16 weight copies.
// GEMM1 (gemm_h): [4096x1024]·[4096x1024]^T -> H bf16, relu, 1024 blocks.
// GEMM2: split-K x4 (gemm_p, f32 partials) + reduce_k(+bias) -> f32 out.
//        Fix for r4's measured starvation: 256 blocks = 1/CU, Occ 10.6%,
//        MfmaUtil 15%. Split-K gives 1024 blocks = 4/CU.
// ---------------------------------------------------------------------------

typedef __attribute__((ext_vector_type(8))) short bf16x8;   // 8 bf16 = 4 VGPR
typedef __attribute__((ext_vector_type(4))) float f32x4;
typedef __attribute__((ext_vector_type(8))) unsigned short u16x8;

__device__ __forceinline__ unsigned short f2bf(float f) {
  unsigned int x = __float_as_uint(f);
  x += 0x7fffu + ((x >> 16) & 1u);        // round-to-nearest-even
  return (unsigned short)(x >> 16);
}

__device__ __forceinline__ void softmax3(const float* __restrict__ p, float* o) {
  float m = fmaxf(p[0], fmaxf(p[1], p[2]));
  float e0 = expf(p[0] - m), e1 = expf(p[1] - m), e2 = expf(p[2] - m);
  float inv = 1.0f / (e0 + e1 + e2);
  o[0] = e0 * inv; o[1] = e1 * inv; o[2] = e2 * inv;
}

// s(h,d); sval(h,0) = bm0[h] row-bias scale; sval(0,d) = bm1[d] col-bias scale
__device__ __forceinline__ float sval(int h, int d, const float a[3], const float b[3]) {
  constexpr int E[3] = {512, 768, 1024};
  constexpr int R[3] = {2, 3, 4};
  float s = 0.f;
#pragma unroll
  for (int ie = 0; ie < 3; ++ie) {
    if (d < E[ie]) {
      float t = 0.f;
#pragma unroll
      for (int ir = 0; ir < 3; ++ir)
        if (h < E[ie] * R[ir]) t += b[ir];
      s += a[ie] * t;
    }
  }
  return s;
}

// ---------------- prep kernels (memory-bound, vectorized 8 elems/thread) ----

__global__ __launch_bounds__(256) void conv_x(const float* __restrict__ x,
                                              unsigned short* __restrict__ o,
                                              int n8) {
  int t = blockIdx.x * 256 + threadIdx.x;
  if (t >= n8) return;
  const f32x4* p = (const f32x4*)(x + (size_t)t * 8);
  f32x4 v0 = p[0], v1 = p[1];
  u16x8 r;
#pragma unroll
  for (int j = 0; j < 4; ++j) { r[j] = f2bf(v0[j]); r[4 + j] = f2bf(v1[j]); }
  *(u16x8*)(o + (size_t)t * 8) = r;
}

// w0: [4096][1024], elem (h,d). 8 consecutive d share one s (boundaries %8==0).
__global__ __launch_bounds__(256) void conv_w0(const float* __restrict__ w,
                                               const float* __restrict__ ae,
                                               const float* __restrict__ am,
                                               unsigned short* __restrict__ o) {
  int t = blockIdx.x * 256 + threadIdx.x;   // < 524288
  int base = t * 8;
  int h = base >> 10, d = base & 1023;
  float a[3], b[3];
  softmax3(ae, a); softmax3(am, b);
  float s = sval(h, d, a, b);
  const f32x4* p = (const f32x4*)(w + (size_t)base);
  f32x4 v0 = p[0], v1 = p[1];
  u16x8 r;
#pragma unroll
  for (int j = 0; j < 4; ++j) { r[j] = f2bf(v0[j] * s); r[4 + j] = f2bf(v1[j] * s); }
  *(u16x8*)(o + (size_t)base) = r;
}

// w1: [1024][4096], elem (d,h). 8 consecutive h share one s (thresholds %8==0).
__global__ __launch_bounds__(256) void conv_w1(const float* __restrict__ w,
                                               const float* __restrict__ ae,
                                               const float* __restrict__ am,
                                               unsigned short* __restrict__ o) {
  int t = blockIdx.x * 256 + threadIdx.x;   // < 524288
  int base = t * 8;
  int d = base >> 12, h = base & 4095;
  float a[3], b[3];
  softmax3(ae, a); softmax3(am, b);
  float s = sval(h, d, a, b);
  const f32x4* p = (const f32x4*)(w + (size_t)base);
  f32x4 v0 = p[0], v1 = p[1];
  u16x8 r;
#pragma unroll
  for (int j = 0; j < 4; ++j) { r[j] = f2bf(v0[j] * s); r[4 + j] = f2bf(v1[j] * s); }
  *(u16x8*)(o + (size_t)base) = r;
}

__global__ __launch_bounds__(256) void conv_bias(const float* __restrict__ b0,
                                                 const float* __restrict__ b1,
                                                 const float* __restrict__ ae,
                                                 const float* __restrict__ am,
                                                 float* __restrict__ bb0,
                                                 float* __restrict__ bb1) {
  int i = blockIdx.x * 256 + threadIdx.x;
  float a[3], b[3];
  softmax3(ae, a); softmax3(am, b);
  if (i < 4096) bb0[i] = sval(i, 0, a, b) * b0[i];
  int d = i - 4096;
  if (d >= 0 && d < 1024) bb1[d] = sval(0, d, a, b) * b1[d];
}

// ---------------- bf16 MFMA GEMM core, B^T layout (m97 structure) -----------
// C[M][N] = A[M][K(chunk)] · B[N][K(chunk)]^T; 128x128 tile, BK=64, 4 waves.
// MODE 0: +bias, relu, bf16 store.  MODE 1: +bias, f32 store.
// MODE 2: f32 partial store to Cout + blockIdx.z*M*N (no bias); chunk
//         kbeg = blockIdx.z*Ksub.

template <int MODE>
__device__ __forceinline__ void gemm_core(const unsigned short* __restrict__ A,
                                          const unsigned short* __restrict__ B,
                                          const float* __restrict__ bias,
                                          void* __restrict__ Cout,
                                          int M, int N, int K, int Ksub) {
  __shared__ unsigned short As[128 * 64];   // 16 KiB
  __shared__ unsigned short Bs[128 * 64];   // 16 KiB

  const int tid  = threadIdx.x;
  const int lane = tid & 63;
  const int w    = tid >> 6;
  const int m0   = blockIdx.x * 128;
  const int n0   = blockIdx.y * 128;
  const int wm   = (w >> 1) * 64;
  const int wn   = (w & 1) * 64;
  const int kbeg = (MODE == 2) ? blockIdx.z * Ksub : 0;
  const int kend = kbeg + Ksub;

  f32x4 acc[4][4] = {};

  // staging geometry: thread t covers 8 bf16 (16 B); 256 threads = 32 rows/iter
  const int srow = tid >> 3;          // 0..31
  const int scol = (tid & 7) * 8;     // 0,8,...,56
  const unsigned short* Ag = A + (size_t)(m0 + srow) * K + scol;
  const unsigned short* Bg = B + (size_t)(n0 + srow) * K + scol;
  unsigned short* Asl = As + tid * 8; // lane-linear dest (wave-uniform base + lane*16B)
  unsigned short* Bsl = Bs + tid * 8;

  for (int k0 = kbeg; k0 < kend; k0 += 64) {
    __syncthreads();                  // prev tile consumed before overwrite
#pragma unroll
    for (int i = 0; i < 4; ++i) {
      __builtin_amdgcn_global_load_lds(
          (const __attribute__((address_space(1))) void*)(Ag + (size_t)(i * 32) * K + k0),
          (__attribute__((address_space(3))) void*)(Asl + i * 2048), 16, 0, 0);
      __builtin_amdgcn_global_load_lds(
          (const __attribute__((address_space(1))) void*)(Bg + (size_t)(i * 32) * K + k0),
          (__attribute__((address_space(3))) void*)(Bsl + i * 2048), 16, 0, 0);
    }
    asm volatile("s_waitcnt vmcnt(0)" ::: "memory");
    __syncthreads();

#pragma unroll
    for (int ks = 0; ks < 2; ++ks) {
      const int ko = ks * 32 + (lane >> 4) * 8;
      bf16x8 af[4], bfr[4];
#pragma unroll
      for (int m = 0; m < 4; ++m)
        af[m] = *(const bf16x8*)&As[(wm + m * 16 + (lane & 15)) * 64 + ko];
#pragma unroll
      for (int n = 0; n < 4; ++n)
        bfr[n] = *(const bf16x8*)&Bs[(wn + n * 16 + (lane & 15)) * 64 + ko];
#pragma unroll
      for (int m = 0; m < 4; ++m)
#pragma unroll
        for (int n = 0; n < 4; ++n)
          acc[m][n] = __builtin_amdgcn_mfma_f32_16x16x32_bf16(af[m], bfr[n], acc[m][n], 0, 0, 0);
    }
  }

  // epilogue: C/D layout col=lane&15, row=(lane>>4)*4+reg  [m89-verified]
  const int crow = (lane >> 4) * 4;
  const int ccol = lane & 15;
#pragma unroll
  for (int m = 0; m < 4; ++m) {
#pragma unroll
    for (int n = 0; n < 4; ++n) {
      const int gr = m0 + wm + m * 16 + crow;
      const int gc = n0 + wn + n * 16 + ccol;
      if (MODE == 0) {
        const float bv = bias[gc];
        unsigned short* H = (unsigned short*)Cout;
#pragma unroll
        for (int r = 0; r < 4; ++r) {
          float v = fmaxf(acc[m][n][r] + bv, 0.f);
          H[(size_t)(gr + r) * N + gc] = f2bf(v);
        }
      } else if (MODE == 1) {
        const float bv = bias[gc];
        float* C = (float*)Cout;
#pragma unroll
        for (int r = 0; r < 4; ++r)
          C[(size_t)(gr + r) * N + gc] = acc[m][n][r] + bv;
      } else {
        float* P = (float*)Cout + (size_t)blockIdx.z * M * N;
#pragma unroll
        for (int r = 0; r < 4; ++r)
          P[(size_t)(gr + r) * N + gc] = acc[m][n][r];
      }
    }
  }
}

__global__ __launch_bounds__(256) void gemm_h(const unsigned short* __restrict__ A,
                                              const unsigned short* __restrict__ B,
                                              const float* __restrict__ bias,
                                              void* __restrict__ C,
                                              int M, int N, int K, int Ksub) {
  gemm_core<0>(A, B, bias, C, M, N, K, Ksub);
}
__global__ __launch_bounds__(256) void gemm_f(const unsigned short* __restrict__ A,
                                              const unsigned short* __restrict__ B,
                                              const float* __restrict__ bias,
                                              void* __restrict__ C,
                                              int M, int N, int K, int Ksub) {
  gemm_core<1>(A, B, bias, C, M, N, K, Ksub);
}
__global__ __launch_bounds__(256) void gemm_p(const unsigned short* __restrict__ A,
                                              const unsigned short* __restrict__ B,
                                              const float* __restrict__ bias,
                                              void* __restrict__ C,
                                              int M, int N, int K, int Ksub) {
  gemm_core<2>(A, B, bias, C, M, N, K, Ksub);
}

// reduce 4 f32 partials + bias -> out.  n4 = MN/4 in f32x4 units.
__global__ __launch_bounds__(256) void reduce_k(const float* __restrict__ P,
                                                const float* __restrict__ bb1,
                                                float* __restrict__ out,
                                                int n4) {
  const f32x4* p = (const f32x4*)P;
  const f32x4* bv = (const f32x4*)bb1;
  f32x4* o = (f32x4*)out;
  for (int i = blockIdx.x * 256 + threadIdx.x; i < n4; i += gridDim.x * 256) {
    f32x4 v = p[i];
    v += p[i + n4];
    v += p[i + 2 * n4];
    v += p[i + 3 * n4];
    v += bv[i & 255];                  // col = (i*4) % 1024
    o[i] = v;
  }
}

// ---------------------------------------------------------------------------

extern "C" void kernel_launch(void* const* d_in, const int* in_sizes, int n_in,
                              void* d_out, int out_size, void* d_ws, size_t ws_size,
                              hipStream_t stream) {
  const float* x  = (const float*)d_in[0];   // [8,512,1024]
  const float* w0 = (const float*)d_in[1];   // [4096,1024]
  const float* b0 = (const float*)d_in[2];   // [4096]
  const float* w1 = (const float*)d_in[3];   // [1024,4096]
  const float* b1 = (const float*)d_in[4];   // [1024]
  const float* ae = (const float*)d_in[5];   // [3]
  const float* am = (const float*)d_in[6];   // [3]

  char* ws = (char*)d_ws;
  unsigned short* xb   = (unsigned short*)(ws);                    //  8 MiB
  unsigned short* w0e  = (unsigned short*)(ws + (8u  << 20));      //  8 MiB
  unsigned short* w1e  = (unsigned short*)(ws + (16u << 20));      //  8 MiB
  unsigned short* Hbuf = (unsigned short*)(ws + (24u << 20));      // 32 MiB
  float* bb0 = (float*)(ws + (56u << 20));                         // 16 KiB
  float* bb1 = (float*)(ws + (56u << 20) + 16384);                 //  4 KiB
  float* part = (float*)(ws + (57u << 20));                        // 64 MiB (split-K)
  const size_t WS_NEEDED = (57u << 20) + (64u << 20);              // 121 MiB

  conv_x  <<<2048, 256, 0, stream>>>(x, xb, 524288);
  conv_w0 <<<2048, 256, 0, stream>>>(w0, ae, am, w0e);
  conv_w1 <<<2048, 256, 0, stream>>>(w1, ae, am, w1e);
  conv_bias<<<20, 256, 0, stream>>>(b0, b1, ae, am, bb0, bb1);

  dim3 g1(32, 32);  // M/128 x N/128
  gemm_h<<<g1, 256, 0, stream>>>(xb, w0e, bb0, Hbuf, 4096, 4096, 1024, 1024);

  if (ws_size >= WS_NEEDED) {
    // split-K x4: 32x8x4 = 1024 blocks (4/CU) vs 256 (1/CU) single-pass
    dim3 g2(32, 8, 4);
    gemm_p<<<g2, 256, 0, stream>>>(Hbuf, w1e, nullptr, part, 4096, 1024, 4096, 1024);
    reduce_k<<<2048, 256, 0, stream>>>(part, bb1, (float*)d_out, 1024 * 1024);
  } else {
    dim3 g2(32, 8);
    gemm_f<<<g2, 256, 0, stream>>>(Hbuf, w1e, bb1, d_out, 4096, 1024, 4096, 4096);
  }
}

// Round 7
// 217.286 us; speedup vs baseline: 1.1081x; 1.0290x over previous
//
#include <hip/hip_runtime.h>

// ---------------------------------------------------------------------------
// MixedFeedForward: out = relu(x·(s⊙w0)^T + sb0⊙b0)·(s⊙w1)^T + sb1⊙b1
// s(h,d) piecewise-constant DARTS mask; folded into bf16 weight copies (one
// fused conv kernel). GEMM1 (gemm_h) 4096x4096x1024 -> bf16 H + relu.
// GEMM2 split-K x4 (gemm_p) + reduce_k(+bias) -> f32 out.
// r6: 2-phase double-buffered K-loop (T3-minimum): stage(t+1) BEFORE
//     compute(t), counted s_waitcnt vmcnt(8), RAW s_barrier (never drain
//     vmcnt at barriers — __syncthreads would). Fix for r5's measured
//     latency-bound GEMMs (MfmaUtil 22%, VALUBusy 24%, Occ 18%).
// ---------------------------------------------------------------------------

typedef __attribute__((ext_vector_type(8))) short bf16x8;   // 8 bf16 = 4 VGPR
typedef __attribute__((ext_vector_type(4))) float f32x4;
typedef __attribute__((ext_vector_type(8))) unsigned short u16x8;

__device__ __forceinline__ unsigned short f2bf(float f) {
  unsigned int x = __float_as_uint(f);
  x += 0x7fffu + ((x >> 16) & 1u);        // round-to-nearest-even
  return (unsigned short)(x >> 16);
}

__device__ __forceinline__ void softmax3(const float* __restrict__ p, float* o) {
  float m = fmaxf(p[0], fmaxf(p[1], p[2]));
  float e0 = expf(p[0] - m), e1 = expf(p[1] - m), e2 = expf(p[2] - m);
  float inv = 1.0f / (e0 + e1 + e2);
  o[0] = e0 * inv; o[1] = e1 * inv; o[2] = e2 * inv;
}

// s(h,d); sval(h,0) = bm0[h] row-bias scale; sval(0,d) = bm1[d] col-bias scale
__device__ __forceinline__ float sval(int h, int d, const float a[3], const float b[3]) {
  constexpr int E[3] = {512, 768, 1024};
  constexpr int R[3] = {2, 3, 4};
  float s = 0.f;
#pragma unroll
  for (int ie = 0; ie < 3; ++ie) {
    if (d < E[ie]) {
      float t = 0.f;
#pragma unroll
      for (int ir = 0; ir < 3; ++ir)
        if (h < E[ie] * R[ir]) t += b[ir];
      s += a[ie] * t;
    }
  }
  return s;
}

// ---------------- fused prep kernel (1 launch instead of 4) ----------------
// segment 0: x cast (524288 x 8 elems); 1: w0 scale+cast; 2: w1 scale+cast;
// 3: biases (640 x 8). Mask thresholds are %8==0 so s uniform per 8-chunk.

__device__ __forceinline__ void cvt8(const float* __restrict__ src,
                                     unsigned short* __restrict__ dst,
                                     size_t base, float s) {
  const f32x4* p = (const f32x4*)(src + base);
  f32x4 v0 = p[0], v1 = p[1];
  u16x8 r;
#pragma unroll
  for (int j = 0; j < 4; ++j) { r[j] = f2bf(v0[j] * s); r[4 + j] = f2bf(v1[j] * s); }
  *(u16x8*)(dst + base) = r;
}

__global__ __launch_bounds__(256) void conv_all(const float* __restrict__ x,
                                                const float* __restrict__ w0,
                                                const float* __restrict__ b0,
                                                const float* __restrict__ w1,
                                                const float* __restrict__ b1,
                                                const float* __restrict__ ae,
                                                const float* __restrict__ am,
                                                unsigned short* __restrict__ xb,
                                                unsigned short* __restrict__ w0e,
                                                unsigned short* __restrict__ w1e,
                                                float* __restrict__ bb0,
                                                float* __restrict__ bb1) {
  int t = blockIdx.x * 256 + threadIdx.x;
  float a[3], b[3];
  softmax3(ae, a); softmax3(am, b);
  if (t < 524288) {
    cvt8(x, xb, (size_t)t * 8, 1.0f);
  } else if (t < 1048576) {
    int base = (t - 524288) * 8;
    cvt8(w0, w0e, base, sval(base >> 10, base & 1023, a, b));   // (h,d)
  } else if (t < 1572864) {
    int base = (t - 1048576) * 8;
    cvt8(w1, w1e, base, sval(base & 4095, base >> 12, a, b));   // (d,h): s(h,d)
  } else if (t < 1573504) {
    int base = (t - 1572864) * 8;
#pragma unroll
    for (int j = 0; j < 8; ++j) {
      int i = base + j;
      if (i < 4096) bb0[i] = sval(i, 0, a, b) * b0[i];
      else          bb1[i - 4096] = sval(0, i - 4096, a, b) * b1[i - 4096];
    }
  }
}

// ---------------- bf16 MFMA GEMM core, B^T layout, 2-phase dbuf -------------
// C[M][N] = A[M][Kchunk] · B[N][Kchunk]^T; 128x128 tile, BK=64, 4 waves.
// MODE 0: +bias, relu, bf16.  MODE 1: +bias, f32.  MODE 2: f32 partial at
// Cout + blockIdx.z*M*N, kbeg = blockIdx.z*Ksub.

template <int MODE>
__device__ __forceinline__ void gemm_core(const unsigned short* __restrict__ A,
                                          const unsigned short* __restrict__ B,
                                          const float* __restrict__ bias,
                                          void* __restrict__ Cout,
                                          int M, int N, int K, int Ksub) {
  __shared__ unsigned short As[2][128 * 64];   // 2 x 16 KiB
  __shared__ unsigned short Bs[2][128 * 64];   // 2 x 16 KiB

  const int tid  = threadIdx.x;
  const int lane = tid & 63;
  const int w    = tid >> 6;
  const int m0   = blockIdx.x * 128;
  const int n0   = blockIdx.y * 128;
  const int wm   = (w >> 1) * 64;
  const int wn   = (w & 1) * 64;
  const int kbeg = (MODE == 2) ? blockIdx.z * Ksub : 0;
  const int nt   = Ksub >> 6;

  f32x4 acc[4][4] = {};

  // staging: thread t covers 16 B; 256 thr = 32 rows/instr; 8 VMEM/wave/tile
  const int srow = tid >> 3;          // 0..31
  const int scol = (tid & 7) * 8;     // 0,8,...,56
  const unsigned short* Ag = A + (size_t)(m0 + srow) * K + scol;
  const unsigned short* Bg = B + (size_t)(n0 + srow) * K + scol;

  auto stage = [&](int buf, int k0) {
#pragma unroll
    for (int i = 0; i < 4; ++i) {
      __builtin_amdgcn_global_load_lds(
          (const __attribute__((address_space(1))) void*)(Ag + (size_t)(i * 32) * K + k0),
          (__attribute__((address_space(3))) void*)(&As[buf][0] + tid * 8 + i * 2048), 16, 0, 0);
      __builtin_amdgcn_global_load_lds(
          (const __attribute__((address_space(1))) void*)(Bg + (size_t)(i * 32) * K + k0),
          (__attribute__((address_space(3))) void*)(&Bs[buf][0] + tid * 8 + i * 2048), 16, 0, 0);
    }
  };

  stage(0, kbeg);                     // prologue: 8 VMEM in flight
  int cur = 0;
  for (int t = 0; t < nt; ++t) {
    const int k0 = kbeg + t * 64;
    if (t + 1 < nt) {
      stage(cur ^ 1, k0 + 64);        // 16 in flight
      asm volatile("s_waitcnt vmcnt(8)" ::: "memory");   // buf[cur] landed
    } else {
      asm volatile("s_waitcnt vmcnt(0)" ::: "memory");
    }
    __builtin_amdgcn_s_barrier();     // RAW barrier: next-tile loads stay in flight
    asm volatile("" ::: "memory");

#pragma unroll
    for (int ks = 0; ks < 2; ++ks) {
      const int ko = ks * 32 + (lane >> 4) * 8;
      bf16x8 af[4], bfr[4];
#pragma unroll
      for (int m = 0; m < 4; ++m)
        af[m] = *(const bf16x8*)&As[cur][(wm + m * 16 + (lane & 15)) * 64 + ko];
#pragma unroll
      for (int n = 0; n < 4; ++n)
        bfr[n] = *(const bf16x8*)&Bs[cur][(wn + n * 16 + (lane & 15)) * 64 + ko];
#pragma unroll
      for (int m = 0; m < 4; ++m)
#pragma unroll
        for (int n = 0; n < 4; ++n)
          acc[m][n] = __builtin_amdgcn_mfma_f32_16x16x32_bf16(af[m], bfr[n], acc[m][n], 0, 0, 0);
    }

    // drain this wave's LDS reads, then sync: after this barrier buf[cur]
    // may be re-staged by any wave (t+1 stages buf[cur^1]^1 = buf[cur]).
    asm volatile("s_waitcnt lgkmcnt(0)" ::: "memory");
    __builtin_amdgcn_s_barrier();
    cur ^= 1;
  }

  // epilogue: C/D layout col=lane&15, row=(lane>>4)*4+reg  [m89-verified]
  const int crow = (lane >> 4) * 4;
  const int ccol = lane & 15;
#pragma unroll
  for (int m = 0; m < 4; ++m) {
#pragma unroll
    for (int n = 0; n < 4; ++n) {
      const int gr = m0 + wm + m * 16 + crow;
      const int gc = n0 + wn + n * 16 + ccol;
      if (MODE == 0) {
        const float bv = bias[gc];
        unsigned short* H = (unsigned short*)Cout;
#pragma unroll
        for (int r = 0; r < 4; ++r) {
          float v = fmaxf(acc[m][n][r] + bv, 0.f);
          H[(size_t)(gr + r) * N + gc] = f2bf(v);
        }
      } else if (MODE == 1) {
        const float bv = bias[gc];
        float* C = (float*)Cout;
#pragma unroll
        for (int r = 0; r < 4; ++r)
          C[(size_t)(gr + r) * N + gc] = acc[m][n][r] + bv;
      } else {
        float* P = (float*)Cout + (size_t)blockIdx.z * M * N;
#pragma unroll
        for (int r = 0; r < 4; ++r)
          P[(size_t)(gr + r) * N + gc] = acc[m][n][r];
      }
    }
  }
}

__global__ __launch_bounds__(256) void gemm_h(const unsigned short* __restrict__ A,
                                              const unsigned short* __restrict__ B,
                                              const float* __restrict__ bias,
                                              void* __restrict__ C,
                                              int M, int N, int K, int Ksub) {
  gemm_core<0>(A, B, bias, C, M, N, K, Ksub);
}
__global__ __launch_bounds__(256) void gemm_f(const unsigned short* __restrict__ A,
                                              const unsigned short* __restrict__ B,
                                              const float* __restrict__ bias,
                                              void* __restrict__ C,
                                              int M, int N, int K, int Ksub) {
  gemm_core<1>(A, B, bias, C, M, N, K, Ksub);
}
__global__ __launch_bounds__(256) void gemm_p(const unsigned short* __restrict__ A,
                                              const unsigned short* __restrict__ B,
                                              const float* __restrict__ bias,
                                              void* __restrict__ C,
                                              int M, int N, int K, int Ksub) {
  gemm_core<2>(A, B, bias, C, M, N, K, Ksub);
}

// reduce 4 f32 partials + bias -> out.  n4 = MN/4 in f32x4 units.
__global__ __launch_bounds__(256) void reduce_k(const float* __restrict__ P,
                                                const float* __restrict__ bb1,
                                                float* __restrict__ out,
                                                int n4) {
  const f32x4* p = (const f32x4*)P;
  const f32x4* bv = (const f32x4*)bb1;
  f32x4* o = (f32x4*)out;
  for (int i = blockIdx.x * 256 + threadIdx.x; i < n4; i += gridDim.x * 256) {
    f32x4 v = p[i];
    v += p[i + n4];
    v += p[i + 2 * n4];
    v += p[i + 3 * n4];
    v += bv[i & 255];                  // col = (i*4) % 1024
    o[i] = v;
  }
}

// ---------------------------------------------------------------------------

extern "C" void kernel_launch(void* const* d_in, const int* in_sizes, int n_in,
                              void* d_out, int out_size, void* d_ws, size_t ws_size,
                              hipStream_t stream) {
  const float* x  = (const float*)d_in[0];   // [8,512,1024]
  const float* w0 = (const float*)d_in[1];   // [4096,1024]
  const float* b0 = (const float*)d_in[2];   // [4096]
  const float* w1 = (const float*)d_in[3];   // [1024,4096]
  const float* b1 = (const float*)d_in[4];   // [1024]
  const float* ae = (const float*)d_in[5];   // [3]
  const float* am = (const float*)d_in[6];   // [3]

  char* ws = (char*)d_ws;
  unsigned short* xb   = (unsigned short*)(ws);                    //  8 MiB
  unsigned short* w0e  = (unsigned short*)(ws + (8u  << 20));      //  8 MiB
  unsigned short* w1e  = (unsigned short*)(ws + (16u << 20));      //  8 MiB
  unsigned short* Hbuf = (unsigned short*)(ws + (24u << 20));      // 32 MiB
  float* bb0 = (float*)(ws + (56u << 20));                         // 16 KiB
  float* bb1 = (float*)(ws + (56u << 20) + 16384);                 //  4 KiB
  float* part = (float*)(ws + (57u << 20));                        // 64 MiB (split-K)
  const size_t WS_NEEDED = (57u << 20) + (64u << 20);              // 121 MiB

  conv_all<<<6147, 256, 0, stream>>>(x, w0, b0, w1, b1, ae, am,
                                     xb, w0e, w1e, bb0, bb1);

  dim3 g1(32, 32);  // M/128 x N/128
  gemm_h<<<g1, 256, 0, stream>>>(xb, w0e, bb0, Hbuf, 4096, 4096, 1024, 1024);

  if (ws_size >= WS_NEEDED) {
    // split-K x4: 32x8x4 = 1024 blocks (4/CU) vs 256 (1/CU) single-pass
    dim3 g2(32, 8, 4);
    gemm_p<<<g2, 256, 0, stream>>>(Hbuf, w1e, nullptr, part, 4096, 1024, 4096, 1024);
    reduce_k<<<2048, 256, 0, stream>>>(part, bb1, (float*)d_out, 1024 * 1024);
  } else {
    dim3 g2(32, 8);
    gemm_f<<<g2, 256, 0, stream>>>(Hbuf, w1e, bb1, d_out, 4096, 1024, 4096, 4096);
  }
}

// Round 9
// 189.183 us; speedup vs baseline: 1.2727x; 1.1486x over previous
//
#include <hip/hip_runtime.h>

// ---------------------------------------------------------------------------
// MixedFeedForward: out = relu(x·(s⊙w0)^T + sb0⊙b0)·(s⊙w1)^T + sb1⊙b1
// r8: 256x256 phase-split GEMM (T2+T3+T4+T5 bundle, plain-HIP port of the
//     verified 8-phase template): BK=64, 8 waves (2Mx4N), 128KiB dyn LDS,
//     K-half staging (2 gload_lds per half-tile), counted vmcnt(4) at each
//     ks-group boundary (never drain mid-loop), 2-way-free LDS swizzle
//     (storage chunk ^= (row>>1)&3, both-sides: inv-swizzled global source +
//     swizzled ds_read), setprio(1) around MFMA clusters.
//     r7 evidence: 2-phase null (58 µs, MfmaUtil 22%) — matches guide's
//     regime gate; counted-vmcnt phase-split is the prerequisite lever.
// ---------------------------------------------------------------------------

typedef __attribute__((ext_vector_type(8))) short bf16x8;   // 8 bf16 = 4 VGPR
typedef __attribute__((ext_vector_type(4))) float f32x4;
typedef __attribute__((ext_vector_type(8))) unsigned short u16x8;

#define AS1 __attribute__((address_space(1)))
#define AS3 __attribute__((address_space(3)))

__device__ __forceinline__ unsigned short f2bf(float f) {
  unsigned int x = __float_as_uint(f);
  x += 0x7fffu + ((x >> 16) & 1u);        // round-to-nearest-even
  return (unsigned short)(x >> 16);
}

__device__ __forceinline__ void softmax3(const float* __restrict__ p, float* o) {
  float m = fmaxf(p[0], fmaxf(p[1], p[2]));
  float e0 = expf(p[0] - m), e1 = expf(p[1] - m), e2 = expf(p[2] - m);
  float inv = 1.0f / (e0 + e1 + e2);
  o[0] = e0 * inv; o[1] = e1 * inv; o[2] = e2 * inv;
}

// s(h,d); sval(h,0) = bm0[h] row-bias scale; sval(0,d) = bm1[d] col-bias scale
__device__ __forceinline__ float sval(int h, int d, const float a[3], const float b[3]) {
  constexpr int E[3] = {512, 768, 1024};
  constexpr int R[3] = {2, 3, 4};
  float s = 0.f;
#pragma unroll
  for (int ie = 0; ie < 3; ++ie) {
    if (d < E[ie]) {
      float t = 0.f;
#pragma unroll
      for (int ir = 0; ir < 3; ++ir)
        if (h < E[ie] * R[ir]) t += b[ir];
      s += a[ie] * t;
    }
  }
  return s;
}

// ---------------- fused prep kernel --------------------------------------

__device__ __forceinline__ void cvt8(const float* __restrict__ src,
                                     unsigned short* __restrict__ dst,
                                     size_t base, float s) {
  const f32x4* p = (const f32x4*)(src + base);
  f32x4 v0 = p[0], v1 = p[1];
  u16x8 r;
#pragma unroll
  for (int j = 0; j < 4; ++j) { r[j] = f2bf(v0[j] * s); r[4 + j] = f2bf(v1[j] * s); }
  *(u16x8*)(dst + base) = r;
}

__global__ __launch_bounds__(256) void conv_all(const float* __restrict__ x,
                                                const float* __restrict__ w0,
                                                const float* __restrict__ b0,
                                                const float* __restrict__ w1,
                                                const float* __restrict__ b1,
                                                const float* __restrict__ ae,
                                                const float* __restrict__ am,
                                                unsigned short* __restrict__ xb,
                                                unsigned short* __restrict__ w0e,
                                                unsigned short* __restrict__ w1e,
                                                float* __restrict__ bb0,
                                                float* __restrict__ bb1) {
  int t = blockIdx.x * 256 + threadIdx.x;
  float a[3], b[3];
  softmax3(ae, a); softmax3(am, b);
  if (t < 524288) {
    cvt8(x, xb, (size_t)t * 8, 1.0f);
  } else if (t < 1048576) {
    int base = (t - 524288) * 8;
    cvt8(w0, w0e, base, sval(base >> 10, base & 1023, a, b));   // (h,d)
  } else if (t < 1572864) {
    int base = (t - 1048576) * 8;
    cvt8(w1, w1e, base, sval(base & 4095, base >> 12, a, b));   // (d,h): s(h,d)
  } else if (t < 1573504) {
    int base = (t - 1572864) * 8;
#pragma unroll
    for (int j = 0; j < 8; ++j) {
      int i = base + j;
      if (i < 4096) bb0[i] = sval(i, 0, a, b) * b0[i];
      else          bb1[i - 4096] = sval(0, i - 4096, a, b) * b1[i - 4096];
    }
  }
}

// ---------------- 256x256 phase-split bf16 MFMA GEMM, B^T layout ------------
// C[M][N] = A[M][Kchunk]·B[N][Kchunk]^T. 8 waves: wm=(wid>>2)*128, wn=(wid&3)*64.
// LDS (dynamic 128KiB): As[2 buf][2 kshalf][256 rows][32 elems] then Bs same.
// Swizzle: storage 16B-chunk cs = logical cl ^ ((row>>1)&3)  (involution).
// MODE 0: +bias, relu, bf16 store. MODE 1: +bias, f32. MODE 2: f32 partial
// at Cout + blockIdx.z*M*N, kbeg = blockIdx.z*Ksub.

template <int MODE>
__global__ __launch_bounds__(512, 2) void gemm256(const unsigned short* __restrict__ A,
                                                  const unsigned short* __restrict__ B,
                                                  const float* __restrict__ bias,
                                                  void* __restrict__ Cout,
                                                  int M, int N, int K, int Ksub) {
  extern __shared__ unsigned short lds[];   // 65536 ushorts = 128 KiB

  const int tid  = threadIdx.x;
  const int lane = tid & 63;
  const int wid  = tid >> 6;
  const int m0   = blockIdx.x * 256;
  const int n0   = blockIdx.y * 256;
  const int wm   = (wid >> 2) * 128;
  const int wn   = (wid & 3) * 64;
  const int kbeg = (MODE == 2) ? blockIdx.z * Ksub : 0;
  const int nt   = Ksub >> 6;

  f32x4 acc[8][4] = {};

  // staging geometry: K-half = 256 rows x 32 elems (64B/row) = 2 instrs.
  // instr covers 128 rows: thread t -> row t>>2, storage chunk t&3.
  // global source chunk = (t&3) ^ ((t>>3)&3)   [inverse swizzle, (row>>1)&3]
  const int srow   = tid >> 2;                       // 0..127
  const int schunk = (tid & 3) ^ ((tid >> 3) & 3);
  const unsigned short* Ag = A + (size_t)(m0 + srow) * K + schunk * 8;
  const unsigned short* Bg = B + (size_t)(n0 + srow) * K + schunk * 8;
  const size_t rstep = (size_t)128 * K;

  auto stageA = [&](int buf, int h, int k) {
    unsigned short* d = lds + (buf * 2 + h) * 8192 + tid * 8;   // linear dest
    __builtin_amdgcn_global_load_lds((const AS1 void*)(Ag + k + h * 32),
                                     (AS3 void*)d, 16, 0, 0);
    __builtin_amdgcn_global_load_lds((const AS1 void*)(Ag + rstep + k + h * 32),
                                     (AS3 void*)(d + 4096), 16, 0, 0);
  };
  auto stageB = [&](int buf, int h, int k) {
    unsigned short* d = lds + 32768 + (buf * 2 + h) * 8192 + tid * 8;
    __builtin_amdgcn_global_load_lds((const AS1 void*)(Bg + k + h * 32),
                                     (AS3 void*)d, 16, 0, 0);
    __builtin_amdgcn_global_load_lds((const AS1 void*)(Bg + rstep + k + h * 32),
                                     (AS3 void*)(d + 4096), 16, 0, 0);
  };

  // read swizzle: within-half col elems = (lane>>4)*8 ^ ((lane>>1)&3)*8
  // row = (tile rows are 16-aligned) -> (row>>1)&3 == (lane>>1)&3
  const int rc = ((lane >> 4) * 8) ^ (((lane >> 1) & 3) << 3);
  const int ra = (lane & 15) * 32 + rc;

  // prologue: tile 0, order [A-K0, B-K0, A-K1, B-K1] = 8 loads
  stageA(0, 0, kbeg); stageB(0, 0, kbeg);
  stageA(0, 1, kbeg); stageB(0, 1, kbeg);

  int buf = 0;
  for (int T = 0; T < nt; ++T) {
    const int kn = kbeg + T * 64 + 64;
    const bool pf = (T + 1 < nt);
    bf16x8 af[4], bfr[4];
    const int ab = (buf * 2) * 8192;            // As ks=0 base
    const int bb = 32768 + (buf * 2) * 8192;    // Bs ks=0 base

    // ===================== ks = 0 group =====================
    // targets: A-K0(T), B-K0(T) (oldest 4 of the 8 outstanding)
    asm volatile("s_waitcnt vmcnt(4)" ::: "memory");
    __builtin_amdgcn_s_barrier();
    asm volatile("" ::: "memory");
    if (pf) stageA(buf ^ 1, 0, kn);
    // phase 0: m-tiles 0..3
#pragma unroll
    for (int n = 0; n < 4; ++n)
      bfr[n] = *(const bf16x8*)&lds[bb + (wn + n * 16) * 32 + ra];
#pragma unroll
    for (int m = 0; m < 4; ++m)
      af[m] = *(const bf16x8*)&lds[ab + (wm + m * 16) * 32 + ra];
    __builtin_amdgcn_s_setprio(1);
#pragma unroll
    for (int m = 0; m < 4; ++m)
#pragma unroll
      for (int n = 0; n < 4; ++n)
        acc[m][n] = __builtin_amdgcn_mfma_f32_16x16x32_bf16(af[m], bfr[n], acc[m][n], 0, 0, 0);
    __builtin_amdgcn_s_setprio(0);
    if (pf) stageB(buf ^ 1, 0, kn);
    // phase 1: m-tiles 4..7 (reuse bfr)
#pragma unroll
    for (int m = 0; m < 4; ++m)
      af[m] = *(const bf16x8*)&lds[ab + (wm + 64 + m * 16) * 32 + ra];
    __builtin_amdgcn_s_setprio(1);
#pragma unroll
    for (int m = 0; m < 4; ++m)
#pragma unroll
      for (int n = 0; n < 4; ++n)
        acc[4 + m][n] = __builtin_amdgcn_mfma_f32_16x16x32_bf16(af[m], bfr[n], acc[4 + m][n], 0, 0, 0);
    __builtin_amdgcn_s_setprio(0);

    // ===================== ks = 1 group =====================
    // targets: A-K1(T), B-K1(T); newer issues = this tile's 2 stages (4 loads)
    if (pf) { asm volatile("s_waitcnt vmcnt(4)" ::: "memory"); }
    else    { asm volatile("s_waitcnt vmcnt(0)" ::: "memory"); }
    __builtin_amdgcn_s_barrier();
    asm volatile("" ::: "memory");
    if (pf) stageA(buf ^ 1, 1, kn);
    // phase 2: m-tiles 0..3
#pragma unroll
    for (int n = 0; n < 4; ++n)
      bfr[n] = *(const bf16x8*)&lds[bb + 8192 + (wn + n * 16) * 32 + ra];
#pragma unroll
    for (int m = 0; m < 4; ++m)
      af[m] = *(const bf16x8*)&lds[ab + 8192 + (wm + m * 16) * 32 + ra];
    __builtin_amdgcn_s_setprio(1);
#pragma unroll
    for (int m = 0; m < 4; ++m)
#pragma unroll
      for (int n = 0; n < 4; ++n)
        acc[m][n] = __builtin_amdgcn_mfma_f32_16x16x32_bf16(af[m], bfr[n], acc[m][n], 0, 0, 0);
    __builtin_amdgcn_s_setprio(0);
    if (pf) stageB(buf ^ 1, 1, kn);
    // phase 3: m-tiles 4..7
#pragma unroll
    for (int m = 0; m < 4; ++m)
      af[m] = *(const bf16x8*)&lds[ab + 8192 + (wm + 64 + m * 16) * 32 + ra];
    __builtin_amdgcn_s_setprio(1);
#pragma unroll
    for (int m = 0; m < 4; ++m)
#pragma unroll
      for (int n = 0; n < 4; ++n)
        acc[4 + m][n] = __builtin_amdgcn_mfma_f32_16x16x32_bf16(af[m], bfr[n], acc[4 + m][n], 0, 0, 0);
    __builtin_amdgcn_s_setprio(0);

    buf ^= 1;
  }

  // epilogue: C/D layout col=lane&15, row=(lane>>4)*4+reg  [m89-verified]
  const int crow = (lane >> 4) * 4;
  const int ccol = lane & 15;
#pragma unroll
  for (int mi = 0; mi < 8; ++mi) {
#pragma unroll
    for (int n = 0; n < 4; ++n) {
      const int gr = m0 + wm + mi * 16 + crow;
      const int gc = n0 + wn + n * 16 + ccol;
      if (MODE == 0) {
        const float bv = bias[gc];
        unsigned short* H = (unsigned short*)Cout;
#pragma unroll
        for (int r = 0; r < 4; ++r) {
          float v = fmaxf(acc[mi][n][r] + bv, 0.f);
          H[(size_t)(gr + r) * N + gc] = f2bf(v);
        }
      } else if (MODE == 1) {
        const float bv = bias[gc];
        float* C = (float*)Cout;
#pragma unroll
        for (int r = 0; r < 4; ++r)
          C[(size_t)(gr + r) * N + gc] = acc[mi][n][r] + bv;
      } else {
        float* P = (float*)Cout + (size_t)blockIdx.z * M * N;
#pragma unroll
        for (int r = 0; r < 4; ++r)
          P[(size_t)(gr + r) * N + gc] = acc[mi][n][r];
      }
    }
  }
}

// reduce 4 f32 partials + bias -> out.  n4 = MN/4 in f32x4 units.
__global__ __launch_bounds__(256) void reduce_k(const float* __restrict__ P,
                                                const float* __restrict__ bb1,
                                                float* __restrict__ out,
                                                int n4) {
  const f32x4* p = (const f32x4*)P;
  const f32x4* bv = (const f32x4*)bb1;
  f32x4* o = (f32x4*)out;
  for (int i = blockIdx.x * 256 + threadIdx.x; i < n4; i += gridDim.x * 256) {
    f32x4 v = p[i];
    v += p[i + n4];
    v += p[i + 2 * n4];
    v += p[i + 3 * n4];
    v += bv[i & 255];                  // col = (i*4) % 1024
    o[i] = v;
  }
}

// ---------------------------------------------------------------------------

extern "C" void kernel_launch(void* const* d_in, const int* in_sizes, int n_in,
                              void* d_out, int out_size, void* d_ws, size_t ws_size,
                              hipStream_t stream) {
  const float* x  = (const float*)d_in[0];   // [8,512,1024]
  const float* w0 = (const float*)d_in[1];   // [4096,1024]
  const float* b0 = (const float*)d_in[2];   // [4096]
  const float* w1 = (const float*)d_in[3];   // [1024,4096]
  const float* b1 = (const float*)d_in[4];   // [1024]
  const float* ae = (const float*)d_in[5];   // [3]
  const float* am = (const float*)d_in[6];   // [3]

  char* ws = (char*)d_ws;
  unsigned short* xb   = (unsigned short*)(ws);                    //  8 MiB
  unsigned short* w0e  = (unsigned short*)(ws + (8u  << 20));      //  8 MiB
  unsigned short* w1e  = (unsigned short*)(ws + (16u << 20));      //  8 MiB
  unsigned short* Hbuf = (unsigned short*)(ws + (24u << 20));      // 32 MiB
  float* bb0 = (float*)(ws + (56u << 20));                         // 16 KiB
  float* bb1 = (float*)(ws + (56u << 20) + 16384);                 //  4 KiB
  float* part = (float*)(ws + (57u << 20));                        // 64 MiB (split-K)
  const size_t WS_NEEDED = (57u << 20) + (64u << 20);              // 121 MiB

  conv_all<<<6147, 256, 0, stream>>>(x, w0, b0, w1, b1, ae, am,
                                     xb, w0e, w1e, bb0, bb1);

  dim3 g1(16, 16);  // M/256 x N/256
  gemm256<0><<<g1, 512, 131072, stream>>>(xb, w0e, bb0, Hbuf, 4096, 4096, 1024, 1024);

  if (ws_size >= WS_NEEDED) {
    // split-K x4: 16x4x4 = 256 blocks (1/CU, 8 waves each)
    dim3 g2(16, 4, 4);
    gemm256<2><<<g2, 512, 131072, stream>>>(Hbuf, w1e, nullptr, part, 4096, 1024, 4096, 1024);
    reduce_k<<<2048, 256, 0, stream>>>(part, bb1, (float*)d_out, 1024 * 1024);
  } else {
    dim3 g2(16, 4);
    gemm256<1><<<g2, 512, 131072, stream>>>(Hbuf, w1e, bb1, d_out, 4096, 1024, 4096, 4096);
  }
}